// Round 2
// baseline (535.450 us; speedup 1.0000x reference)
//
#include <hip/hip_runtime.h>
#include <hip/hip_bf16.h>

#define N_TOK   4096
#define DM      1024
#define DF      2048
#define NEXP    8
#define NPAIR   (N_TOK * 2)
#define BMT     256     // m-tile
#define BNT     128     // n-tile
#define BKT     64      // k-tile

typedef __attribute__((ext_vector_type(8))) short bf16x8;
typedef __attribute__((ext_vector_type(4))) float f32x4;

__device__ __forceinline__ unsigned short to_bf16(float f) {
    unsigned u = __builtin_bit_cast(unsigned, f);
    unsigned r = (u + 0x7FFFu + ((u >> 16) & 1u)) >> 16;
    return (unsigned short)r;
}
__device__ __forceinline__ unsigned pk_bf16(float a, float b) {
    return (unsigned)to_bf16(a) | ((unsigned)to_bf16(b) << 16);
}
// async global->LDS, 16B per lane; LDS dest = wave-uniform base + lane*16
__device__ __forceinline__ void gld16(const unsigned short* g, unsigned short* l) {
    __builtin_amdgcn_global_load_lds(
        (const __attribute__((address_space(1))) unsigned int*)(g),
        (__attribute__((address_space(3))) unsigned int*)(l), 16, 0, 0);
}

// ---------------- sort pairs by expert ----------------
// meta: [0..8) counts, [8..16) cursors, [16..25) rowOff, [25..34) mtOff, [34] totalMT
__global__ void k_count(const int* __restrict__ eidx, int* __restrict__ meta) {
    int i = blockIdx.x * 256 + threadIdx.x;
    if (i < NPAIR) atomicAdd(&meta[eidx[i] & 7], 1);
}
__global__ void k_scan(int* __restrict__ meta) {
    if (threadIdx.x == 0) {
        int off = 0, mt = 0;
        for (int e = 0; e < NEXP; ++e) {
            meta[16 + e] = off; meta[25 + e] = mt;
            int c = meta[e];
            off += c; mt += (c + BMT - 1) / BMT;
        }
        meta[16 + NEXP] = off; meta[25 + NEXP] = mt; meta[34] = mt;
    }
}
__global__ void k_scatter(const int* __restrict__ eidx, int* __restrict__ meta,
                          int* __restrict__ rows) {
    int i = blockIdx.x * 256 + threadIdx.x;
    if (i < NPAIR) {
        int e = eidx[i] & 7;
        int p = meta[16 + e] + atomicAdd(&meta[8 + e], 1);
        rows[p] = i;
    }
}

// ---------------- pre-passes: dtype conversion + weight transpose ----------------
__global__ __launch_bounds__(256)
void k_cvt_x(const float* __restrict__ x, unsigned short* __restrict__ xb) {
    int i = (blockIdx.x * 256 + threadIdx.x) * 8;
    float4 v0 = *(const float4*)(x + i);
    float4 v1 = *(const float4*)(x + i + 4);
    uint4 w;
    w.x = pk_bf16(v0.x, v0.y); w.y = pk_bf16(v0.z, v0.w);
    w.z = pk_bf16(v1.x, v1.y); w.w = pk_bf16(v1.z, v1.w);
    *(uint4*)(xb + i) = w;
}

// src [E][K][F] fp32 -> dst [E][F][K] bf16.  grid = (F/64, K/64, E), block 256
__global__ __launch_bounds__(256)
void k_transpose(const float* __restrict__ src, unsigned short* __restrict__ dst,
                 int K, int F) {
    __shared__ __align__(16) unsigned short tile[64 * 80];
    const int e  = blockIdx.z;
    const int k0 = blockIdx.y * 64;
    const int f0 = blockIdx.x * 64;
    const int t  = threadIdx.x;
    const float* s = src + (size_t)e * K * F;
    unsigned short* d = dst + (size_t)e * K * F;
    const int fi = t & 63;
    const int kg = t >> 6;
    #pragma unroll
    for (int i = 0; i < 16; ++i) {
        int k = kg * 16 + i;
        tile[k * 80 + fi] = to_bf16(s[(size_t)(k0 + k) * F + f0 + fi]);
    }
    __syncthreads();
    const int kc = (t & 7) * 8;
    const int fo = t >> 3;
    #pragma unroll
    for (int j = 0; j < 2; ++j) {
        int f = fo + j * 32;
        unsigned short v[8];
        #pragma unroll
        for (int i = 0; i < 8; ++i) v[i] = tile[(kc + i) * 80 + f];
        uint4 w;
        w.x = (unsigned)v[0] | ((unsigned)v[1] << 16);
        w.y = (unsigned)v[2] | ((unsigned)v[3] << 16);
        w.z = (unsigned)v[4] | ((unsigned)v[5] << 16);
        w.w = (unsigned)v[6] | ((unsigned)v[7] << 16);
        *(uint4*)&d[(size_t)(f0 + f) * K + k0 + kc] = w;
    }
}

// ---------------- bf16 GEMM1: H = silu(X W1) * (X W2) ----------------
// 512 thr / 8 waves (4Mx2N), 256x128x64 tile, dbuf + counted vmcnt,
// 4 phases/K-tile with double barriers + setprio, XOR bank-swizzle
// (linear LDS dest, swizzled global source, swizzled ds_read).
__global__ __launch_bounds__(512, 2)
void k_gemm1_bf(const unsigned short* __restrict__ xb,
                const unsigned short* __restrict__ w1t,  // [E][F][K=DM]
                const unsigned short* __restrict__ w2t,
                const int* __restrict__ meta,
                const int* __restrict__ rows,
                unsigned short* __restrict__ H)
{
    // per buf: A 32KB (rounds 0-3) | B1 16KB (4-5) | B2 16KB (6-7)
    __shared__ __align__(16) unsigned short L[2][32768];   // 128 KiB
    __shared__ int s_tok[BMT];

    const int mt = blockIdx.y;
    if (mt >= meta[34]) return;
    int e = 0;
    #pragma unroll
    for (int i = 0; i < NEXP - 1; ++i) if (mt >= meta[25 + i + 1]) e = i + 1;
    const int rowEnd = meta[16 + e + 1];
    const int row0   = meta[16 + e] + (mt - meta[25 + e]) * BMT;
    const int f0     = blockIdx.x * BNT;
    const int tid    = threadIdx.x;

    if (tid < BMT) {
        int gr = row0 + tid;
        s_tok[tid] = (gr < rowEnd) ? (rows[gr] >> 1) : 0;
    }
    __syncthreads();

    const int lane = tid & 63;
    const int wid  = tid >> 6;
    // staging: round stages 64 rows; this thread owns row sr, 16B chunk (lane&7)
    const int sr  = wid * 8 + (lane >> 3);               // 0..63
    const int swz = ((lane & 7) ^ ((lane >> 3) & 7)) * 8; // swizzled chunk, in shorts
    const size_t wb = (size_t)e * DM * DF;

    const unsigned short* p0 = xb + (size_t)s_tok[       sr] * DM + swz;
    const unsigned short* p1 = xb + (size_t)s_tok[ 64 +  sr] * DM + swz;
    const unsigned short* p2 = xb + (size_t)s_tok[128 +  sr] * DM + swz;
    const unsigned short* p3 = xb + (size_t)s_tok[192 +  sr] * DM + swz;
    const unsigned short* p4 = w1t + wb + (size_t)(f0 +      sr) * DM + swz;
    const unsigned short* p5 = w1t + wb + (size_t)(f0 + 64 + sr) * DM + swz;
    const unsigned short* p6 = w2t + wb + (size_t)(f0 +      sr) * DM + swz;
    const unsigned short* p7 = w2t + wb + (size_t)(f0 + 64 + sr) * DM + swz;

    f32x4 accg[4][4], accv[4][4];
    #pragma unroll
    for (int i = 0; i < 4; ++i)
        #pragma unroll
        for (int j = 0; j < 4; ++j) { accg[i][j] = (f32x4)0.f; accv[i][j] = (f32x4)0.f; }

    const int wm  = (wid >> 1) * 64;
    const int wn  = (wid & 1) * 64;
    const int am  = lane & 15;
    const int cb  = lane >> 4;          // 0..3 : k-chunk within slice
    const int key = am & 7;             // row&7 for all frag rows
    const int axk0 = ((cb    ) ^ key) << 4;   // byte offset of 16B chunk, kslice 0
    const int axk1 = ((cb + 4) ^ key) << 4;   // kslice 1

    auto stage = [&](int b, int k0) {
        unsigned short* base = &L[0][0] + b * 32768 + wid * 512;
        gld16(p0 + k0, base);
        gld16(p1 + k0, base + 4096);
        gld16(p2 + k0, base + 8192);
        gld16(p3 + k0, base + 12288);
        gld16(p4 + k0, base + 16384);
        gld16(p5 + k0, base + 20480);
        gld16(p6 + k0, base + 24576);
        gld16(p7 + k0, base + 28672);
    };

    stage(0, 0);
    #pragma unroll 1
    for (int t = 0; t < DM / BKT; ++t) {
        const int buf = t & 1;
        if (t < DM / BKT - 1) {
            stage(buf ^ 1, (t + 1) * BKT);
            __builtin_amdgcn_sched_barrier(0);
            asm volatile("s_waitcnt vmcnt(8)" ::: "memory");  // tile t done; t+1 in flight
        } else {
            asm volatile("s_waitcnt vmcnt(0)" ::: "memory");
        }
        __builtin_amdgcn_s_barrier();
        const char* A  = (const char*)(&L[0][0] + buf * 32768);
        const char* B1 = A + 32768;
        const char* B2 = A + 49152;
        #pragma unroll
        for (int ks = 0; ks < 2; ++ks) {
            const int ax = ks ? axk1 : axk0;
            bf16x8 b1[4], b2[4], a[2];
            #pragma unroll
            for (int ni = 0; ni < 4; ++ni) {
                const int n = wn + ni * 16 + am;
                b1[ni] = *(const bf16x8*)(B1 + n * 128 + ax);
                b2[ni] = *(const bf16x8*)(B2 + n * 128 + ax);
            }
            #pragma unroll
            for (int mi = 0; mi < 2; ++mi)
                a[mi] = *(const bf16x8*)(A + (wm + mi * 16 + am) * 128 + ax);
            __builtin_amdgcn_sched_barrier(0);
            __builtin_amdgcn_s_barrier();
            __builtin_amdgcn_s_setprio(1);
            #pragma unroll
            for (int mi = 0; mi < 2; ++mi)
                #pragma unroll
                for (int ni = 0; ni < 4; ++ni) {
                    accg[mi][ni] = __builtin_amdgcn_mfma_f32_16x16x32_bf16(a[mi], b1[ni], accg[mi][ni], 0, 0, 0);
                    accv[mi][ni] = __builtin_amdgcn_mfma_f32_16x16x32_bf16(a[mi], b2[ni], accv[mi][ni], 0, 0, 0);
                }
            __builtin_amdgcn_s_setprio(0);
            __builtin_amdgcn_sched_barrier(0);
            __builtin_amdgcn_s_barrier();
            #pragma unroll
            for (int mi = 0; mi < 2; ++mi)
                a[mi] = *(const bf16x8*)(A + (wm + 32 + mi * 16 + am) * 128 + ax);
            __builtin_amdgcn_sched_barrier(0);
            __builtin_amdgcn_s_barrier();
            __builtin_amdgcn_s_setprio(1);
            #pragma unroll
            for (int mi = 0; mi < 2; ++mi)
                #pragma unroll
                for (int ni = 0; ni < 4; ++ni) {
                    accg[2 + mi][ni] = __builtin_amdgcn_mfma_f32_16x16x32_bf16(a[mi], b1[ni], accg[2 + mi][ni], 0, 0, 0);
                    accv[2 + mi][ni] = __builtin_amdgcn_mfma_f32_16x16x32_bf16(a[mi], b2[ni], accv[2 + mi][ni], 0, 0, 0);
                }
            __builtin_amdgcn_s_setprio(0);
            __builtin_amdgcn_sched_barrier(0);
            __builtin_amdgcn_s_barrier();
        }
    }

    const int cn = lane & 15;
    const int cq = (lane >> 4) * 4;
    #pragma unroll
    for (int mi = 0; mi < 4; ++mi) {
        #pragma unroll
        for (int r = 0; r < 4; ++r) {
            const int row = wm + mi * 16 + cq + r;
            const int gr  = row0 + row;
            if (gr < rowEnd) {
                unsigned short* dst = H + (size_t)gr * DF + f0 + wn;
                #pragma unroll
                for (int ni = 0; ni < 4; ++ni) {
                    float g = accg[mi][ni][r];
                    float v = accv[mi][ni][r];
                    float h = (g * v) / (1.f + __expf(-g));
                    dst[ni * 16 + cn] = to_bf16(h);
                }
            }
        }
    }
}

// ---------------- bf16 GEMM2: out[tok] += w * (H @ W3), K split over blockIdx.z ----------------
__global__ __launch_bounds__(512, 2)
void k_gemm2_bf(const unsigned short* __restrict__ H,
                const unsigned short* __restrict__ w3t,  // [E][D=DM][K=DF]
                const int* __restrict__ meta,
                const int* __restrict__ rows,
                const float* __restrict__ ew,
                float* __restrict__ out)
{
    // per buf: A 32KB (rounds 0-3) | B 16KB (4-5)
    __shared__ __align__(16) unsigned short L[2][24576];   // 96 KiB
    __shared__ int   s_tok[BMT];
    __shared__ float s_w[BMT];

    const int mt = blockIdx.y;
    if (mt >= meta[34]) return;
    int e = 0;
    #pragma unroll
    for (int i = 0; i < NEXP - 1; ++i) if (mt >= meta[25 + i + 1]) e = i + 1;
    const int rowEnd = meta[16 + e + 1];
    const int row0   = meta[16 + e] + (mt - meta[25 + e]) * BMT;
    const int d0     = blockIdx.x * BNT;
    const int kz     = blockIdx.z * (DF / 2);   // 0 or 1024
    const int tid    = threadIdx.x;

    if (tid < BMT) {
        int gr = row0 + tid;
        if (gr < rowEnd) { int pr = rows[gr]; s_tok[tid] = pr >> 1; s_w[tid] = ew[pr]; }
        else             { s_tok[tid] = 0;    s_w[tid] = 0.f; }
    }
    __syncthreads();

    const int lane = tid & 63;
    const int wid  = tid >> 6;
    const int sr   = wid * 8 + (lane >> 3);
    const int swz  = ((lane & 7) ^ ((lane >> 3) & 7)) * 8;
    const size_t wb = (size_t)e * DM * DF;

    int ga0 = row0 +       sr; if (ga0 > NPAIR - 1) ga0 = NPAIR - 1;
    int ga1 = row0 +  64 + sr; if (ga1 > NPAIR - 1) ga1 = NPAIR - 1;
    int ga2 = row0 + 128 + sr; if (ga2 > NPAIR - 1) ga2 = NPAIR - 1;
    int ga3 = row0 + 192 + sr; if (ga3 > NPAIR - 1) ga3 = NPAIR - 1;
    const unsigned short* p0 = H + (size_t)ga0 * DF + kz + swz;
    const unsigned short* p1 = H + (size_t)ga1 * DF + kz + swz;
    const unsigned short* p2 = H + (size_t)ga2 * DF + kz + swz;
    const unsigned short* p3 = H + (size_t)ga3 * DF + kz + swz;
    const unsigned short* p4 = w3t + wb + (size_t)(d0 +      sr) * DF + kz + swz;
    const unsigned short* p5 = w3t + wb + (size_t)(d0 + 64 + sr) * DF + kz + swz;

    f32x4 acc[4][4];
    #pragma unroll
    for (int i = 0; i < 4; ++i)
        #pragma unroll
        for (int j = 0; j < 4; ++j) acc[i][j] = (f32x4)0.f;

    const int wm  = (wid >> 1) * 64;
    const int wn  = (wid & 1) * 64;
    const int am  = lane & 15;
    const int cb  = lane >> 4;
    const int key = am & 7;
    const int axk0 = ((cb    ) ^ key) << 4;
    const int axk1 = ((cb + 4) ^ key) << 4;

    auto stage = [&](int b, int k0) {
        unsigned short* base = &L[0][0] + b * 24576 + wid * 512;
        gld16(p0 + k0, base);
        gld16(p1 + k0, base + 4096);
        gld16(p2 + k0, base + 8192);
        gld16(p3 + k0, base + 12288);
        gld16(p4 + k0, base + 16384);
        gld16(p5 + k0, base + 20480);
    };

    stage(0, 0);
    #pragma unroll 1
    for (int t = 0; t < (DF / 2) / BKT; ++t) {
        const int buf = t & 1;
        if (t < (DF / 2) / BKT - 1) {
            stage(buf ^ 1, (t + 1) * BKT);
            __builtin_amdgcn_sched_barrier(0);
            asm volatile("s_waitcnt vmcnt(6)" ::: "memory");
        } else {
            asm volatile("s_waitcnt vmcnt(0)" ::: "memory");
        }
        __builtin_amdgcn_s_barrier();
        const char* A = (const char*)(&L[0][0] + buf * 24576);
        const char* B = A + 32768;
        #pragma unroll
        for (int ks = 0; ks < 2; ++ks) {
            const int ax = ks ? axk1 : axk0;
            bf16x8 b[4], a[2];
            #pragma unroll
            for (int ni = 0; ni < 4; ++ni)
                b[ni] = *(const bf16x8*)(B + (wn + ni * 16 + am) * 128 + ax);
            #pragma unroll
            for (int mi = 0; mi < 2; ++mi)
                a[mi] = *(const bf16x8*)(A + (wm + mi * 16 + am) * 128 + ax);
            __builtin_amdgcn_sched_barrier(0);
            __builtin_amdgcn_s_barrier();
            __builtin_amdgcn_s_setprio(1);
            #pragma unroll
            for (int mi = 0; mi < 2; ++mi)
                #pragma unroll
                for (int ni = 0; ni < 4; ++ni)
                    acc[mi][ni] = __builtin_amdgcn_mfma_f32_16x16x32_bf16(a[mi], b[ni], acc[mi][ni], 0, 0, 0);
            __builtin_amdgcn_s_setprio(0);
            __builtin_amdgcn_sched_barrier(0);
            __builtin_amdgcn_s_barrier();
            #pragma unroll
            for (int mi = 0; mi < 2; ++mi)
                a[mi] = *(const bf16x8*)(A + (wm + 32 + mi * 16 + am) * 128 + ax);
            __builtin_amdgcn_sched_barrier(0);
            __builtin_amdgcn_s_barrier();
            __builtin_amdgcn_s_setprio(1);
            #pragma unroll
            for (int mi = 0; mi < 2; ++mi)
                #pragma unroll
                for (int ni = 0; ni < 4; ++ni)
                    acc[2 + mi][ni] = __builtin_amdgcn_mfma_f32_16x16x32_bf16(a[mi], b[ni], acc[2 + mi][ni], 0, 0, 0);
            __builtin_amdgcn_s_setprio(0);
            __builtin_amdgcn_sched_barrier(0);
            __builtin_amdgcn_s_barrier();
        }
    }

    const int cn = lane & 15;
    const int cq = (lane >> 4) * 4;
    #pragma unroll
    for (int mi = 0; mi < 4; ++mi) {
        #pragma unroll
        for (int r = 0; r < 4; ++r) {
            const int row = wm + mi * 16 + cq + r;
            const int gr  = row0 + row;
            if (gr < rowEnd) {
                const int   tok = s_tok[row];
                const float wgt = s_w[row];
                float* dst = out + (size_t)tok * DM + d0 + wn;
                #pragma unroll
                for (int ni = 0; ni < 4; ++ni)
                    atomicAdd(&dst[ni * 16 + cn], wgt * acc[mi][ni][r]);
            }
        }
    }
}

// ================= fallback (tiny workspace) =================
__global__ __launch_bounds__(256)
void k_fallback(const float* __restrict__ x, const int* __restrict__ eidx,
                const float* __restrict__ ew, const float* __restrict__ w1,
                const float* __restrict__ w2, const float* __restrict__ w3,
                float* __restrict__ out)
{
    __shared__ float xs[DM];
    __shared__ float hs[DF];
    const int pair = blockIdx.x;
    const int t = pair >> 1;
    const int e = eidx[pair] & 7;
    const float wgt = ew[pair];
    const int tid = threadIdx.x;
    for (int i = tid; i < DM; i += 256) xs[i] = x[(size_t)t * DM + i];
    __syncthreads();
    for (int f = tid; f < DF; f += 256) {
        const float* c1 = w1 + (size_t)e * DM * DF + f;
        const float* c2 = w2 + (size_t)e * DM * DF + f;
        float g = 0.f, v = 0.f;
        for (int d = 0; d < DM; ++d) {
            float xv = xs[d];
            g += xv * c1[(size_t)d * DF];
            v += xv * c2[(size_t)d * DF];
        }
        hs[f] = (g * v) / (1.f + __expf(-g));
    }
    __syncthreads();
    for (int d = tid; d < DM; d += 256) {
        const float* c3 = w3 + (size_t)e * DF * DM + d;
        float o = 0.f;
        for (int f = 0; f < DF; ++f) o += hs[f] * c3[(size_t)f * DM];
        atomicAdd(&out[(size_t)t * DM + d], wgt * o);
    }
}

extern "C" void kernel_launch(void* const* d_in, const int* in_sizes, int n_in,
                              void* d_out, int out_size, void* d_ws, size_t ws_size,
                              hipStream_t stream)
{
    const float* x  = (const float*)d_in[0];
    const int*   ei = (const int*)  d_in[1];
    const float* ew = (const float*)d_in[2];
    const float* w1 = (const float*)d_in[3];
    const float* w2 = (const float*)d_in[4];
    const float* w3 = (const float*)d_in[5];
    float* out = (float*)d_out;

    (void)hipMemsetAsync(d_out, 0, (size_t)out_size * sizeof(float), stream);

    const size_t SZ_H  = (size_t)NPAIR * DF * 2;     // 32 MB
    const size_t SZ_XB = (size_t)N_TOK * DM * 2;     // 8 MB
    const size_t SZ_W  = (size_t)NEXP * DM * DF * 2; // 32 MB each
    const size_t OFF_H  = 65536;
    const size_t OFF_XB = OFF_H + SZ_H;
    const size_t OFF_W1 = OFF_XB + SZ_XB;
    const size_t OFF_W2 = OFF_W1 + SZ_W;
    const size_t OFF_W3 = OFF_W2 + SZ_W;
    const size_t NEED_BIG = OFF_W3 + SZ_W;

    if (ws_size < NEED_BIG) {
        k_fallback<<<NPAIR, 256, 0, stream>>>(x, ei, ew, w1, w2, w3, out);
        return;
    }

    int* meta = (int*)d_ws;
    int* rows = meta + 64;
    unsigned short* H   = (unsigned short*)((char*)d_ws + OFF_H);
    unsigned short* xb  = (unsigned short*)((char*)d_ws + OFF_XB);
    unsigned short* w1t = (unsigned short*)((char*)d_ws + OFF_W1);
    unsigned short* w2t = (unsigned short*)((char*)d_ws + OFF_W2);
    unsigned short* w3t = (unsigned short*)((char*)d_ws + OFF_W3);

    (void)hipMemsetAsync(d_ws, 0, 64, stream);
    k_count  <<<NPAIR / 256, 256, 0, stream>>>(ei, meta);
    k_scan   <<<1, 64, 0, stream>>>(meta);
    k_scatter<<<NPAIR / 256, 256, 0, stream>>>(ei, meta, rows);

    k_cvt_x<<<(N_TOK * DM) / 2048, 256, 0, stream>>>(x, xb);
    k_transpose<<<dim3(DF / 64, DM / 64, NEXP), 256, 0, stream>>>(w1, w1t, DM, DF);
    k_transpose<<<dim3(DF / 64, DM / 64, NEXP), 256, 0, stream>>>(w2, w2t, DM, DF);
    k_transpose<<<dim3(DM / 64, DF / 64, NEXP), 256, 0, stream>>>(w3, w3t, DF, DM);

    const int NMT = NPAIR / BMT + NEXP;  // 40 worst-case m-tiles
    k_gemm1_bf<<<dim3(DF / BNT, NMT),    512, 0, stream>>>(xb, w1t, w2t, meta, rows, H);
    k_gemm2_bf<<<dim3(DM / BNT, NMT, 2), 512, 0, stream>>>(H, w3t, meta, rows, ew, out);
}

// Round 3
// 500.439 us; speedup vs baseline: 1.0700x; 1.0700x over previous
//
#include <hip/hip_runtime.h>
#include <hip/hip_bf16.h>

#define N_TOK   4096
#define DM      1024
#define DF      2048
#define NEXP    8
#define NPAIR   (N_TOK * 2)
#define BM      128
#define BN      128
#define BK      32

typedef __attribute__((ext_vector_type(8))) short bf16x8;
typedef __attribute__((ext_vector_type(4))) float f32x4;

__device__ __forceinline__ unsigned short to_bf16(float f) {
    unsigned u = __builtin_bit_cast(unsigned, f);
    unsigned r = (u + 0x7FFFu + ((u >> 16) & 1u)) >> 16;
    return (unsigned short)r;
}
__device__ __forceinline__ unsigned pk_bf16(float a, float b) {
    return (unsigned)to_bf16(a) | ((unsigned)to_bf16(b) << 16);
}
// async global->LDS, 16B per lane; LDS dest = wave-uniform base + lane*16
__device__ __forceinline__ void gld16(const unsigned short* g, unsigned short* l) {
    __builtin_amdgcn_global_load_lds(
        (const __attribute__((address_space(1))) unsigned int*)(g),
        (__attribute__((address_space(3))) unsigned int*)(l), 16, 0, 0);
}

// ---------------- sort pairs by expert ----------------
// meta: [0..8) counts, [8..16) cursors, [16..25) rowOff, [25..34) mtOff, [34] totalMT
__global__ void k_count(const int* __restrict__ eidx, int* __restrict__ meta) {
    int i = blockIdx.x * 256 + threadIdx.x;
    if (i < NPAIR) atomicAdd(&meta[eidx[i] & 7], 1);
}
__global__ void k_scan(int* __restrict__ meta) {
    if (threadIdx.x == 0) {
        int off = 0, mt = 0;
        for (int e = 0; e < NEXP; ++e) {
            meta[16 + e] = off; meta[25 + e] = mt;
            int c = meta[e];
            off += c; mt += (c + BM - 1) / BM;
        }
        meta[16 + NEXP] = off; meta[25 + NEXP] = mt; meta[34] = mt;
    }
}
__global__ void k_scatter(const int* __restrict__ eidx, int* __restrict__ meta,
                          int* __restrict__ rows) {
    int i = blockIdx.x * 256 + threadIdx.x;
    if (i < NPAIR) {
        int e = eidx[i] & 7;
        int p = meta[16 + e] + atomicAdd(&meta[8 + e], 1);
        rows[p] = i;
    }
}

// ---------------- pre-passes: dtype conversion + weight transpose ----------------
__global__ __launch_bounds__(256)
void k_cvt_x(const float* __restrict__ x, unsigned short* __restrict__ xb) {
    int i = (blockIdx.x * 256 + threadIdx.x) * 8;
    float4 v0 = *(const float4*)(x + i);
    float4 v1 = *(const float4*)(x + i + 4);
    uint4 w;
    w.x = pk_bf16(v0.x, v0.y); w.y = pk_bf16(v0.z, v0.w);
    w.z = pk_bf16(v1.x, v1.y); w.w = pk_bf16(v1.z, v1.w);
    *(uint4*)(xb + i) = w;
}

// src [E][K][F] fp32 -> dst [E][F][K] bf16.  grid = (F/64, K/64, E), block 256
__global__ __launch_bounds__(256)
void k_transpose(const float* __restrict__ src, unsigned short* __restrict__ dst,
                 int K, int F) {
    __shared__ __align__(16) unsigned short tile[64 * 80];
    const int e  = blockIdx.z;
    const int k0 = blockIdx.y * 64;
    const int f0 = blockIdx.x * 64;
    const int t  = threadIdx.x;
    const float* s = src + (size_t)e * K * F;
    unsigned short* d = dst + (size_t)e * K * F;
    const int fi = t & 63;
    const int kg = t >> 6;
    #pragma unroll
    for (int i = 0; i < 16; ++i) {
        int k = kg * 16 + i;
        tile[k * 80 + fi] = to_bf16(s[(size_t)(k0 + k) * F + f0 + fi]);
    }
    __syncthreads();
    const int kc = (t & 7) * 8;
    const int fo = t >> 3;
    #pragma unroll
    for (int j = 0; j < 2; ++j) {
        int f = fo + j * 32;
        unsigned short v[8];
        #pragma unroll
        for (int i = 0; i < 8; ++i) v[i] = tile[(kc + i) * 80 + f];
        uint4 w;
        w.x = (unsigned)v[0] | ((unsigned)v[1] << 16);
        w.y = (unsigned)v[2] | ((unsigned)v[3] << 16);
        w.z = (unsigned)v[4] | ((unsigned)v[5] << 16);
        w.w = (unsigned)v[6] | ((unsigned)v[7] << 16);
        *(uint4*)&d[(size_t)(f0 + f) * K + k0 + kc] = w;
    }
}

// ---------------- bf16 GEMM1: H = silu(X W1) * (X W2) ----------------
// R0 structure + 3-buffer LDS pipeline (prefetch distance 2, counted vmcnt).
// Per buf: A 8KB | B1 8KB | B2 8KB = 24KB; 3 bufs = 72KB -> 2 blocks/CU.
__global__ __launch_bounds__(256, 2)
void k_gemm1_bf(const unsigned short* __restrict__ xb,
                const unsigned short* __restrict__ w1t,  // [E][F][K=DM]
                const unsigned short* __restrict__ w2t,
                const int* __restrict__ meta,
                const int* __restrict__ rows,
                unsigned short* __restrict__ H)
{
    __shared__ __align__(16) unsigned short L[3][12288];
    __shared__ int s_tok[BM];

    const int mt = blockIdx.y;
    if (mt >= meta[34]) return;
    int e = 0;
    #pragma unroll
    for (int i = 0; i < NEXP - 1; ++i) if (mt >= meta[25 + i + 1]) e = i + 1;
    const int rowEnd = meta[16 + e + 1];
    const int row0   = meta[16 + e] + (mt - meta[25 + e]) * BM;
    const int f0     = blockIdx.x * BN;
    const int tid    = threadIdx.x;

    if (tid < BM) {
        int gr = row0 + tid;
        s_tok[tid] = (gr < rowEnd) ? (rows[gr] >> 1) : 0;
    }
    __syncthreads();

    const int lane = tid & 63;
    const int wave = tid >> 6;
    // staging: lane owns row wave*32 + lane/4 (+16 for 2nd call), k-elems (lane&3)*8..+8
    const int r0 = wave * 32 + (lane >> 2);
    const int r1 = r0 + 16;
    const int kb = (lane & 3) * 8;
    const unsigned short* a_src0 = xb + (size_t)s_tok[r0] * DM + kb;
    const unsigned short* a_src1 = xb + (size_t)s_tok[r1] * DM + kb;
    const size_t wb = (size_t)e * DM * DF;
    const unsigned short* b1_src0 = w1t + wb + (size_t)(f0 + r0) * DM + kb;
    const unsigned short* b1_src1 = w1t + wb + (size_t)(f0 + r1) * DM + kb;
    const unsigned short* b2_src0 = w2t + wb + (size_t)(f0 + r0) * DM + kb;
    const unsigned short* b2_src1 = w2t + wb + (size_t)(f0 + r1) * DM + kb;

    f32x4 accg[4][4], accv[4][4];
    #pragma unroll
    for (int i = 0; i < 4; ++i)
        #pragma unroll
        for (int j = 0; j < 4; ++j) { accg[i][j] = (f32x4)0.f; accv[i][j] = (f32x4)0.f; }

    const int wm = (wave >> 1) * 64;
    const int wn = (wave & 1) * 64;
    const int am = lane & 15;
    const int ak = (lane >> 4) * 8;

    auto stage = [&](int b, int k0) {
        unsigned short* base = &L[b][0] + wave * 1024;
        gld16(a_src0  + k0, base);
        gld16(a_src1  + k0, base + 512);
        gld16(b1_src0 + k0, base + 4096);
        gld16(b1_src1 + k0, base + 4608);
        gld16(b2_src0 + k0, base + 8192);
        gld16(b2_src1 + k0, base + 8704);
    };
    auto compute = [&](int b) {
        const unsigned short* Ab = &L[b][0];
        bf16x8 a[4], b1[4], b2[4];
        #pragma unroll
        for (int mi = 0; mi < 4; ++mi)
            a[mi] = *(const bf16x8*)&Ab[(wm + mi * 16 + am) * BK + ak];
        #pragma unroll
        for (int ni = 0; ni < 4; ++ni) {
            b1[ni] = *(const bf16x8*)&Ab[4096 + (wn + ni * 16 + am) * BK + ak];
            b2[ni] = *(const bf16x8*)&Ab[8192 + (wn + ni * 16 + am) * BK + ak];
        }
        #pragma unroll
        for (int mi = 0; mi < 4; ++mi)
            #pragma unroll
            for (int ni = 0; ni < 4; ++ni) {
                accg[mi][ni] = __builtin_amdgcn_mfma_f32_16x16x32_bf16(a[mi], b1[ni], accg[mi][ni], 0, 0, 0);
                accv[mi][ni] = __builtin_amdgcn_mfma_f32_16x16x32_bf16(a[mi], b2[ni], accv[mi][ni], 0, 0, 0);
            }
    };

    // prologue: two tiles in flight
    stage(0, 0);
    stage(1, BK);
    for (int t = 0; t < DM / BK; ++t) {
        const int b = t % 3;
        if (t < DM / BK - 2) {
            stage((t + 2) % 3, (t + 2) * BK);
            asm volatile("s_waitcnt vmcnt(12)" ::: "memory");  // tile t done; t+1,t+2 in flight
        } else if (t == DM / BK - 2) {
            asm volatile("s_waitcnt vmcnt(6)" ::: "memory");
        } else {
            asm volatile("s_waitcnt vmcnt(0)" ::: "memory");
        }
        __builtin_amdgcn_s_barrier();        // all waves' tile-t writes landed
        __builtin_amdgcn_sched_barrier(0);
        compute(b);
        __builtin_amdgcn_sched_barrier(0);
        __builtin_amdgcn_s_barrier();        // all reads of buf b done -> reusable
    }

    const int cn = lane & 15;
    const int cq = (lane >> 4) * 4;
    #pragma unroll
    for (int mi = 0; mi < 4; ++mi) {
        #pragma unroll
        for (int r = 0; r < 4; ++r) {
            const int row = wm + mi * 16 + cq + r;
            const int gr  = row0 + row;
            if (gr < rowEnd) {
                unsigned short* dst = H + (size_t)gr * DF + f0 + wn;
                #pragma unroll
                for (int ni = 0; ni < 4; ++ni) {
                    float g = accg[mi][ni][r];
                    float v = accv[mi][ni][r];
                    float h = (g * v) / (1.f + __expf(-g));
                    dst[ni * 16 + cn] = to_bf16(h);
                }
            }
        }
    }
}

// ---------------- bf16 GEMM2: out[tok] += w * (H @ W3) ----------------
// Same 3-buffer pipeline; per buf A 8KB + B 8KB = 16KB; 3 bufs = 48KB -> 3 blocks/CU.
__global__ __launch_bounds__(256, 2)
void k_gemm2_bf(const unsigned short* __restrict__ H,
                const unsigned short* __restrict__ w3t,  // [E][D=DM][K=DF]
                const int* __restrict__ meta,
                const int* __restrict__ rows,
                const float* __restrict__ ew,
                float* __restrict__ out)
{
    __shared__ __align__(16) unsigned short L[3][8192];
    __shared__ int   s_tok[BM];
    __shared__ float s_w[BM];

    const int mt = blockIdx.y;
    if (mt >= meta[34]) return;
    int e = 0;
    #pragma unroll
    for (int i = 0; i < NEXP - 1; ++i) if (mt >= meta[25 + i + 1]) e = i + 1;
    const int rowEnd = meta[16 + e + 1];
    const int row0   = meta[16 + e] + (mt - meta[25 + e]) * BM;
    const int d0     = blockIdx.x * BN;
    const int tid    = threadIdx.x;

    if (tid < BM) {
        int gr = row0 + tid;
        if (gr < rowEnd) { int pr = rows[gr]; s_tok[tid] = pr >> 1; s_w[tid] = ew[pr]; }
        else             { s_tok[tid] = 0;    s_w[tid] = 0.f; }
    }
    __syncthreads();

    const int lane = tid & 63;
    const int wave = tid >> 6;
    const int r0 = wave * 32 + (lane >> 2);
    const int r1 = r0 + 16;
    const int kb = (lane & 3) * 8;
    int gr0 = row0 + r0; if (gr0 > NPAIR - 1) gr0 = NPAIR - 1;
    int gr1 = row0 + r1; if (gr1 > NPAIR - 1) gr1 = NPAIR - 1;
    const unsigned short* a_src0 = H + (size_t)gr0 * DF + kb;
    const unsigned short* a_src1 = H + (size_t)gr1 * DF + kb;
    const size_t wb = (size_t)e * DM * DF;
    const unsigned short* b_src0 = w3t + wb + (size_t)(d0 + r0) * DF + kb;
    const unsigned short* b_src1 = w3t + wb + (size_t)(d0 + r1) * DF + kb;

    f32x4 acc[4][4];
    #pragma unroll
    for (int i = 0; i < 4; ++i)
        #pragma unroll
        for (int j = 0; j < 4; ++j) acc[i][j] = (f32x4)0.f;

    const int wm = (wave >> 1) * 64;
    const int wn = (wave & 1) * 64;
    const int am = lane & 15;
    const int ak = (lane >> 4) * 8;

    auto stage = [&](int b, int k0) {
        unsigned short* base = &L[b][0] + wave * 1024;
        gld16(a_src0 + k0, base);
        gld16(a_src1 + k0, base + 512);
        gld16(b_src0 + k0, base + 4096);
        gld16(b_src1 + k0, base + 4608);
    };
    auto compute = [&](int b) {
        const unsigned short* Ab = &L[b][0];
        bf16x8 a[4], bfr[4];
        #pragma unroll
        for (int mi = 0; mi < 4; ++mi)
            a[mi] = *(const bf16x8*)&Ab[(wm + mi * 16 + am) * BK + ak];
        #pragma unroll
        for (int ni = 0; ni < 4; ++ni)
            bfr[ni] = *(const bf16x8*)&Ab[4096 + (wn + ni * 16 + am) * BK + ak];
        #pragma unroll
        for (int mi = 0; mi < 4; ++mi)
            #pragma unroll
            for (int ni = 0; ni < 4; ++ni)
                acc[mi][ni] = __builtin_amdgcn_mfma_f32_16x16x32_bf16(a[mi], bfr[ni], acc[mi][ni], 0, 0, 0);
    };

    stage(0, 0);
    stage(1, BK);
    for (int t = 0; t < DF / BK; ++t) {
        const int b = t % 3;
        if (t < DF / BK - 2) {
            stage((t + 2) % 3, (t + 2) * BK);
            asm volatile("s_waitcnt vmcnt(8)" ::: "memory");
        } else if (t == DF / BK - 2) {
            asm volatile("s_waitcnt vmcnt(4)" ::: "memory");
        } else {
            asm volatile("s_waitcnt vmcnt(0)" ::: "memory");
        }
        __builtin_amdgcn_s_barrier();
        __builtin_amdgcn_sched_barrier(0);
        compute(b);
        __builtin_amdgcn_sched_barrier(0);
        __builtin_amdgcn_s_barrier();
    }

    const int cn = lane & 15;
    const int cq = (lane >> 4) * 4;
    #pragma unroll
    for (int mi = 0; mi < 4; ++mi) {
        #pragma unroll
        for (int r = 0; r < 4; ++r) {
            const int row = wm + mi * 16 + cq + r;
            const int gr  = row0 + row;
            if (gr < rowEnd) {
                const int   tok = s_tok[row];
                const float wgt = s_w[row];
                float* dst = out + (size_t)tok * DM + d0 + wn;
                #pragma unroll
                for (int ni = 0; ni < 4; ++ni)
                    atomicAdd(&dst[ni * 16 + cn], wgt * acc[mi][ni][r]);
            }
        }
    }
}

// ================= fallback (tiny workspace) =================
__global__ __launch_bounds__(256)
void k_fallback(const float* __restrict__ x, const int* __restrict__ eidx,
                const float* __restrict__ ew, const float* __restrict__ w1,
                const float* __restrict__ w2, const float* __restrict__ w3,
                float* __restrict__ out)
{
    __shared__ float xs[DM];
    __shared__ float hs[DF];
    const int pair = blockIdx.x;
    const int t = pair >> 1;
    const int e = eidx[pair] & 7;
    const float wgt = ew[pair];
    const int tid = threadIdx.x;
    for (int i = tid; i < DM; i += 256) xs[i] = x[(size_t)t * DM + i];
    __syncthreads();
    for (int f = tid; f < DF; f += 256) {
        const float* c1 = w1 + (size_t)e * DM * DF + f;
        const float* c2 = w2 + (size_t)e * DM * DF + f;
        float g = 0.f, v = 0.f;
        for (int d = 0; d < DM; ++d) {
            float xv = xs[d];
            g += xv * c1[(size_t)d * DF];
            v += xv * c2[(size_t)d * DF];
        }
        hs[f] = (g * v) / (1.f + __expf(-g));
    }
    __syncthreads();
    for (int d = tid; d < DM; d += 256) {
        const float* c3 = w3 + (size_t)e * DF * DM + d;
        float o = 0.f;
        for (int f = 0; f < DF; ++f) o += hs[f] * c3[(size_t)f * DM];
        atomicAdd(&out[(size_t)t * DM + d], wgt * o);
    }
}

extern "C" void kernel_launch(void* const* d_in, const int* in_sizes, int n_in,
                              void* d_out, int out_size, void* d_ws, size_t ws_size,
                              hipStream_t stream)
{
    const float* x  = (const float*)d_in[0];
    const int*   ei = (const int*)  d_in[1];
    const float* ew = (const float*)d_in[2];
    const float* w1 = (const float*)d_in[3];
    const float* w2 = (const float*)d_in[4];
    const float* w3 = (const float*)d_in[5];
    float* out = (float*)d_out;

    (void)hipMemsetAsync(d_out, 0, (size_t)out_size * sizeof(float), stream);

    const size_t SZ_H  = (size_t)NPAIR * DF * 2;     // 32 MB
    const size_t SZ_XB = (size_t)N_TOK * DM * 2;     // 8 MB
    const size_t SZ_W  = (size_t)NEXP * DM * DF * 2; // 32 MB each
    const size_t OFF_H  = 65536;
    const size_t OFF_XB = OFF_H + SZ_H;
    const size_t OFF_W1 = OFF_XB + SZ_XB;
    const size_t OFF_W2 = OFF_W1 + SZ_W;
    const size_t OFF_W3 = OFF_W2 + SZ_W;
    const size_t NEED_BIG = OFF_W3 + SZ_W;

    if (ws_size < NEED_BIG) {
        k_fallback<<<NPAIR, 256, 0, stream>>>(x, ei, ew, w1, w2, w3, out);
        return;
    }

    int* meta = (int*)d_ws;
    int* rows = meta + 64;
    unsigned short* H   = (unsigned short*)((char*)d_ws + OFF_H);
    unsigned short* xb  = (unsigned short*)((char*)d_ws + OFF_XB);
    unsigned short* w1t = (unsigned short*)((char*)d_ws + OFF_W1);
    unsigned short* w2t = (unsigned short*)((char*)d_ws + OFF_W2);
    unsigned short* w3t = (unsigned short*)((char*)d_ws + OFF_W3);

    (void)hipMemsetAsync(d_ws, 0, 64, stream);
    k_count  <<<NPAIR / 256, 256, 0, stream>>>(ei, meta);
    k_scan   <<<1, 64, 0, stream>>>(meta);
    k_scatter<<<NPAIR / 256, 256, 0, stream>>>(ei, meta, rows);

    k_cvt_x<<<(N_TOK * DM) / 2048, 256, 0, stream>>>(x, xb);
    k_transpose<<<dim3(DF / 64, DM / 64, NEXP), 256, 0, stream>>>(w1, w1t, DM, DF);
    k_transpose<<<dim3(DF / 64, DM / 64, NEXP), 256, 0, stream>>>(w2, w2t, DM, DF);
    k_transpose<<<dim3(DM / 64, DF / 64, NEXP), 256, 0, stream>>>(w3, w3t, DF, DM);

    const int NMT = NPAIR / BM + NEXP;
    k_gemm1_bf<<<dim3(DF / BN, NMT), 256, 0, stream>>>(xb, w1t, w2t, meta, rows, H);
    k_gemm2_bf<<<dim3(DM / BN, NMT), 256, 0, stream>>>(H, w3t, meta, rows, ew, out);
}

// Round 4
// 418.993 us; speedup vs baseline: 1.2779x; 1.1944x over previous
//
#include <hip/hip_runtime.h>
#include <hip/hip_bf16.h>

#define N_TOK   4096
#define DM      1024
#define DF      2048
#define NEXP    8
#define NPAIR   (N_TOK * 2)
#define BM      128
#define BN      128
#define BK      32

typedef __attribute__((ext_vector_type(8))) short bf16x8;
typedef __attribute__((ext_vector_type(4))) float f32x4;

__device__ __forceinline__ unsigned short to_bf16(float f) {
    unsigned u = __builtin_bit_cast(unsigned, f);
    unsigned r = (u + 0x7FFFu + ((u >> 16) & 1u)) >> 16;
    return (unsigned short)r;
}
__device__ __forceinline__ unsigned pk_bf16(float a, float b) {
    return (unsigned)to_bf16(a) | ((unsigned)to_bf16(b) << 16);
}
// async global->LDS, 16B per lane; LDS dest = wave-uniform base + lane*16
__device__ __forceinline__ void gld16(const unsigned short* g, unsigned short* l) {
    __builtin_amdgcn_global_load_lds(
        (const __attribute__((address_space(1))) unsigned int*)(g),
        (__attribute__((address_space(3))) unsigned int*)(l), 16, 0, 0);
}

// ---------------- single-kernel sort of pairs by expert ----------------
// meta: [16..25) rowOff, [25..34) mtOff, [34] totalMT
__global__ __launch_bounds__(1024)
void k_sort(const int* __restrict__ eidx, int* __restrict__ meta,
            int* __restrict__ rows) {
    __shared__ int cnt[NEXP];
    __shared__ int cur[NEXP];
    const int tid = threadIdx.x;
    if (tid < NEXP) cnt[tid] = 0;
    __syncthreads();
    #pragma unroll
    for (int i = tid; i < NPAIR; i += 1024) atomicAdd(&cnt[eidx[i] & 7], 1);
    __syncthreads();
    if (tid == 0) {
        int off = 0, mt = 0;
        for (int e = 0; e < NEXP; ++e) {
            meta[16 + e] = off; meta[25 + e] = mt; cur[e] = off;
            int c = cnt[e];
            off += c; mt += (c + BM - 1) / BM;
        }
        meta[16 + NEXP] = off; meta[25 + NEXP] = mt; meta[34] = mt;
    }
    __syncthreads();
    #pragma unroll
    for (int i = tid; i < NPAIR; i += 1024) {
        int e = eidx[i] & 7;
        int p = atomicAdd(&cur[e], 1);
        rows[p] = i;
    }
}

// ---------------- merged pre-pass: x->bf16 + 3 weight transposes ----------------
__device__ __forceinline__ void d_transpose(const float* __restrict__ src,
                                            unsigned short* __restrict__ dst,
                                            int K, int F, int e, int bx, int by,
                                            unsigned short* tile, int t) {
    const int k0 = by * 64;
    const int f0 = bx * 64;
    const float* s = src + (size_t)e * K * F;
    unsigned short* d = dst + (size_t)e * K * F;
    const int fi = t & 63;
    const int kg = t >> 6;
    #pragma unroll
    for (int i = 0; i < 16; ++i) {
        int k = kg * 16 + i;
        tile[k * 80 + fi] = to_bf16(s[(size_t)(k0 + k) * F + f0 + fi]);
    }
    __syncthreads();
    const int kc = (t & 7) * 8;
    const int fo = t >> 3;
    #pragma unroll
    for (int j = 0; j < 2; ++j) {
        int f = fo + j * 32;
        unsigned short v[8];
        #pragma unroll
        for (int i = 0; i < 8; ++i) v[i] = tile[(kc + i) * 80 + f];
        uint4 w;
        w.x = (unsigned)v[0] | ((unsigned)v[1] << 16);
        w.y = (unsigned)v[2] | ((unsigned)v[3] << 16);
        w.z = (unsigned)v[4] | ((unsigned)v[5] << 16);
        w.w = (unsigned)v[6] | ((unsigned)v[7] << 16);
        *(uint4*)&d[(size_t)(f0 + f) * K + k0 + kc] = w;
    }
}

// blocks: [0,2048) cvt_x | [2048,6144) w1 | [6144,10240) w2 | [10240,14336) w3
__global__ __launch_bounds__(256)
void k_prepass(const float* __restrict__ x, unsigned short* __restrict__ xb,
               const float* __restrict__ w1, unsigned short* __restrict__ w1t,
               const float* __restrict__ w2, unsigned short* __restrict__ w2t,
               const float* __restrict__ w3, unsigned short* __restrict__ w3t) {
    __shared__ __align__(16) unsigned short tile[64 * 80];
    const int b = blockIdx.x;
    const int t = threadIdx.x;
    if (b < 2048) {
        int i = (b * 256 + t) * 8;
        float4 v0 = *(const float4*)(x + i);
        float4 v1 = *(const float4*)(x + i + 4);
        uint4 w;
        w.x = pk_bf16(v0.x, v0.y); w.y = pk_bf16(v0.z, v0.w);
        w.z = pk_bf16(v1.x, v1.y); w.w = pk_bf16(v1.z, v1.w);
        *(uint4*)(xb + i) = w;
    } else if (b < 6144) {
        int l = b - 2048;            // K=DM (16 y-blocks), F=DF (32 x-blocks), 512/e
        int e = l >> 9, rem = l & 511;
        d_transpose(w1, w1t, DM, DF, e, rem & 31, rem >> 5, tile, t);
    } else if (b < 10240) {
        int l = b - 6144;
        int e = l >> 9, rem = l & 511;
        d_transpose(w2, w2t, DM, DF, e, rem & 31, rem >> 5, tile, t);
    } else {
        int l = b - 10240;           // K=DF (32 y-blocks), F=DM (16 x-blocks), 512/e
        int e = l >> 9, rem = l & 511;
        d_transpose(w3, w3t, DF, DM, e, rem & 15, rem >> 4, tile, t);
    }
}

// ---------------- XCD-chunked block remap ----------------
// XCD x = bid&7 gets a contiguous chunk of m-tiles; inside the chunk, ordering is
// n-group-major so consecutive same-XCD blocks reuse the same B-panel in that
// XCD's L2, and the chunk's A-tiles (~2.3MB) stay L2-resident across n-groups.
// Returns false for surplus blocks.
__device__ __forceinline__ bool xcd_map(const int* meta, int bid, int ngroups,
                                        int& mt, int& ng) {
    const int MT = meta[34];
    const int x = bid & 7;
    const int j = bid >> 3;
    const int q = MT >> 3, r = MT & 7;
    const int Sx = q + (x < r ? 1 : 0);
    if (Sx == 0 || j >= Sx * ngroups) return false;
    ng = j / Sx;
    const int mtl = j - ng * Sx;
    mt = x * q + (x < r ? x : r) + mtl;
    return true;
}

// ---------------- bf16 GEMM1: H = silu(X W1) * (X W2) ----------------
// R0 inner loop (best measured) + XCD-chunked remap.
__global__ __launch_bounds__(256, 2)
void k_gemm1_bf(const unsigned short* __restrict__ xb,
                const unsigned short* __restrict__ w1t,  // [E][F][K=DM]
                const unsigned short* __restrict__ w2t,
                const int* __restrict__ meta,
                const int* __restrict__ rows,
                unsigned short* __restrict__ H)
{
    __shared__ __align__(16) unsigned short As [BM * BK];
    __shared__ __align__(16) unsigned short B1s[BN * BK];
    __shared__ __align__(16) unsigned short B2s[BN * BK];
    __shared__ int s_tok[BM];

    int mt, ng;
    if (!xcd_map(meta, blockIdx.x, DF / BN, mt, ng)) return;
    int e = 0;
    #pragma unroll
    for (int i = 0; i < NEXP - 1; ++i) if (mt >= meta[25 + i + 1]) e = i + 1;
    const int rowEnd = meta[16 + e + 1];
    const int row0   = meta[16 + e] + (mt - meta[25 + e]) * BM;
    const int f0     = ng * BN;
    const int tid    = threadIdx.x;

    if (tid < BM) {
        int gr = row0 + tid;
        s_tok[tid] = (gr < rowEnd) ? (rows[gr] >> 1) : 0;
    }
    __syncthreads();

    const int lane = tid & 63;
    const int wave = tid >> 6;
    const int r0 = wave * 32 + (lane >> 2);
    const int r1 = r0 + 16;
    const int kb = (lane & 3) * 8;
    const unsigned short* a_src0 = xb + (size_t)s_tok[r0] * DM + kb;
    const unsigned short* a_src1 = xb + (size_t)s_tok[r1] * DM + kb;
    const size_t wb = (size_t)e * DM * DF;
    const unsigned short* b1_src0 = w1t + wb + (size_t)(f0 + r0) * DM + kb;
    const unsigned short* b1_src1 = w1t + wb + (size_t)(f0 + r1) * DM + kb;
    const unsigned short* b2_src0 = w2t + wb + (size_t)(f0 + r0) * DM + kb;
    const unsigned short* b2_src1 = w2t + wb + (size_t)(f0 + r1) * DM + kb;
    unsigned short* As0  = &As [wave * 1024];
    unsigned short* As1  = &As [wave * 1024 + 512];
    unsigned short* B1s0 = &B1s[wave * 1024];
    unsigned short* B1s1 = &B1s[wave * 1024 + 512];
    unsigned short* B2s0 = &B2s[wave * 1024];
    unsigned short* B2s1 = &B2s[wave * 1024 + 512];

    f32x4 accg[4][4], accv[4][4];
    #pragma unroll
    for (int i = 0; i < 4; ++i)
        #pragma unroll
        for (int j = 0; j < 4; ++j) { accg[i][j] = (f32x4)0.f; accv[i][j] = (f32x4)0.f; }

    const int wm = (wave >> 1) * 64;
    const int wn = (wave & 1) * 64;
    const int am = lane & 15;
    const int ak = (lane >> 4) * 8;

    for (int k0 = 0; k0 < DM; k0 += BK) {
        gld16(a_src0 + k0, As0);
        gld16(a_src1 + k0, As1);
        gld16(b1_src0 + k0, B1s0);
        gld16(b1_src1 + k0, B1s1);
        gld16(b2_src0 + k0, B2s0);
        gld16(b2_src1 + k0, B2s1);
        __syncthreads();

        bf16x8 a[4], b1[4], b2[4];
        #pragma unroll
        for (int mi = 0; mi < 4; ++mi) a[mi] = *(const bf16x8*)&As[(wm + mi * 16 + am) * BK + ak];
        #pragma unroll
        for (int ni = 0; ni < 4; ++ni) {
            b1[ni] = *(const bf16x8*)&B1s[(wn + ni * 16 + am) * BK + ak];
            b2[ni] = *(const bf16x8*)&B2s[(wn + ni * 16 + am) * BK + ak];
        }
        #pragma unroll
        for (int mi = 0; mi < 4; ++mi)
            #pragma unroll
            for (int ni = 0; ni < 4; ++ni) {
                accg[mi][ni] = __builtin_amdgcn_mfma_f32_16x16x32_bf16(a[mi], b1[ni], accg[mi][ni], 0, 0, 0);
                accv[mi][ni] = __builtin_amdgcn_mfma_f32_16x16x32_bf16(a[mi], b2[ni], accv[mi][ni], 0, 0, 0);
            }
        __syncthreads();
    }

    const int cn = lane & 15;
    const int cq = (lane >> 4) * 4;
    #pragma unroll
    for (int mi = 0; mi < 4; ++mi) {
        #pragma unroll
        for (int r = 0; r < 4; ++r) {
            const int row = wm + mi * 16 + cq + r;
            const int gr  = row0 + row;
            if (gr < rowEnd) {
                unsigned short* dst = H + (size_t)gr * DF + f0 + wn;
                #pragma unroll
                for (int ni = 0; ni < 4; ++ni) {
                    float g = accg[mi][ni][r];
                    float v = accv[mi][ni][r];
                    float h = (g * v) / (1.f + __expf(-g));
                    dst[ni * 16 + cn] = to_bf16(h);
                }
            }
        }
    }
}

// ---------------- bf16 GEMM2: out[tok] += w * (H @ W3) ----------------
__global__ __launch_bounds__(256, 2)
void k_gemm2_bf(const unsigned short* __restrict__ H,
                const unsigned short* __restrict__ w3t,  // [E][D=DM][K=DF]
                const int* __restrict__ meta,
                const int* __restrict__ rows,
                const float* __restrict__ ew,
                float* __restrict__ out)
{
    __shared__ __align__(16) unsigned short As[BM * BK];
    __shared__ __align__(16) unsigned short Bs[BN * BK];
    __shared__ int   s_tok[BM];
    __shared__ float s_w[BM];

    int mt, ng;
    if (!xcd_map(meta, blockIdx.x, DM / BN, mt, ng)) return;
    int e = 0;
    #pragma unroll
    for (int i = 0; i < NEXP - 1; ++i) if (mt >= meta[25 + i + 1]) e = i + 1;
    const int rowEnd = meta[16 + e + 1];
    const int row0   = meta[16 + e] + (mt - meta[25 + e]) * BM;
    const int d0     = ng * BN;
    const int tid    = threadIdx.x;

    if (tid < BM) {
        int gr = row0 + tid;
        if (gr < rowEnd) { int pr = rows[gr]; s_tok[tid] = pr >> 1; s_w[tid] = ew[pr]; }
        else             { s_tok[tid] = 0;    s_w[tid] = 0.f; }
    }
    __syncthreads();

    const int lane = tid & 63;
    const int wave = tid >> 6;
    const int r0 = wave * 32 + (lane >> 2);
    const int r1 = r0 + 16;
    const int kb = (lane & 3) * 8;
    int gr0 = row0 + r0; if (gr0 > NPAIR - 1) gr0 = NPAIR - 1;
    int gr1 = row0 + r1; if (gr1 > NPAIR - 1) gr1 = NPAIR - 1;
    const unsigned short* a_src0 = H + (size_t)gr0 * DF + kb;
    const unsigned short* a_src1 = H + (size_t)gr1 * DF + kb;
    const size_t wb = (size_t)e * DM * DF;
    const unsigned short* b_src0 = w3t + wb + (size_t)(d0 + r0) * DF + kb;
    const unsigned short* b_src1 = w3t + wb + (size_t)(d0 + r1) * DF + kb;
    unsigned short* As0 = &As[wave * 1024];
    unsigned short* As1 = &As[wave * 1024 + 512];
    unsigned short* Bs0 = &Bs[wave * 1024];
    unsigned short* Bs1 = &Bs[wave * 1024 + 512];

    f32x4 acc[4][4];
    #pragma unroll
    for (int i = 0; i < 4; ++i)
        #pragma unroll
        for (int j = 0; j < 4; ++j) acc[i][j] = (f32x4)0.f;

    const int wm = (wave >> 1) * 64;
    const int wn = (wave & 1) * 64;
    const int am = lane & 15;
    const int ak = (lane >> 4) * 8;

    for (int k0 = 0; k0 < DF; k0 += BK) {
        gld16(a_src0 + k0, As0);
        gld16(a_src1 + k0, As1);
        gld16(b_src0 + k0, Bs0);
        gld16(b_src1 + k0, Bs1);
        __syncthreads();

        bf16x8 a[4], b[4];
        #pragma unroll
        for (int mi = 0; mi < 4; ++mi) a[mi] = *(const bf16x8*)&As[(wm + mi * 16 + am) * BK + ak];
        #pragma unroll
        for (int ni = 0; ni < 4; ++ni) b[ni] = *(const bf16x8*)&Bs[(wn + ni * 16 + am) * BK + ak];
        #pragma unroll
        for (int mi = 0; mi < 4; ++mi)
            #pragma unroll
            for (int ni = 0; ni < 4; ++ni)
                acc[mi][ni] = __builtin_amdgcn_mfma_f32_16x16x32_bf16(a[mi], b[ni], acc[mi][ni], 0, 0, 0);
        __syncthreads();
    }

    const int cn = lane & 15;
    const int cq = (lane >> 4) * 4;
    #pragma unroll
    for (int mi = 0; mi < 4; ++mi) {
        #pragma unroll
        for (int r = 0; r < 4; ++r) {
            const int row = wm + mi * 16 + cq + r;
            const int gr  = row0 + row;
            if (gr < rowEnd) {
                const int   tok = s_tok[row];
                const float wgt = s_w[row];
                float* dst = out + (size_t)tok * DM + d0 + wn;
                #pragma unroll
                for (int ni = 0; ni < 4; ++ni)
                    atomicAdd(&dst[ni * 16 + cn], wgt * acc[mi][ni][r]);
            }
        }
    }
}

// ================= fallback (tiny workspace) =================
__global__ __launch_bounds__(256)
void k_fallback(const float* __restrict__ x, const int* __restrict__ eidx,
                const float* __restrict__ ew, const float* __restrict__ w1,
                const float* __restrict__ w2, const float* __restrict__ w3,
                float* __restrict__ out)
{
    __shared__ float xs[DM];
    __shared__ float hs[DF];
    const int pair = blockIdx.x;
    const int t = pair >> 1;
    const int e = eidx[pair] & 7;
    const float wgt = ew[pair];
    const int tid = threadIdx.x;
    for (int i = tid; i < DM; i += 256) xs[i] = x[(size_t)t * DM + i];
    __syncthreads();
    for (int f = tid; f < DF; f += 256) {
        const float* c1 = w1 + (size_t)e * DM * DF + f;
        const float* c2 = w2 + (size_t)e * DM * DF + f;
        float g = 0.f, v = 0.f;
        for (int d = 0; d < DM; ++d) {
            float xv = xs[d];
            g += xv * c1[(size_t)d * DF];
            v += xv * c2[(size_t)d * DF];
        }
        hs[f] = (g * v) / (1.f + __expf(-g));
    }
    __syncthreads();
    for (int d = tid; d < DM; d += 256) {
        const float* c3 = w3 + (size_t)e * DF * DM + d;
        float o = 0.f;
        for (int f = 0; f < DF; ++f) o += hs[f] * c3[(size_t)f * DM];
        atomicAdd(&out[(size_t)t * DM + d], wgt * o);
    }
}

extern "C" void kernel_launch(void* const* d_in, const int* in_sizes, int n_in,
                              void* d_out, int out_size, void* d_ws, size_t ws_size,
                              hipStream_t stream)
{
    const float* x  = (const float*)d_in[0];
    const int*   ei = (const int*)  d_in[1];
    const float* ew = (const float*)d_in[2];
    const float* w1 = (const float*)d_in[3];
    const float* w2 = (const float*)d_in[4];
    const float* w3 = (const float*)d_in[5];
    float* out = (float*)d_out;

    (void)hipMemsetAsync(d_out, 0, (size_t)out_size * sizeof(float), stream);

    const size_t SZ_H  = (size_t)NPAIR * DF * 2;     // 32 MB
    const size_t SZ_XB = (size_t)N_TOK * DM * 2;     // 8 MB
    const size_t SZ_W  = (size_t)NEXP * DM * DF * 2; // 32 MB each
    const size_t OFF_H  = 65536;
    const size_t OFF_XB = OFF_H + SZ_H;
    const size_t OFF_W1 = OFF_XB + SZ_XB;
    const size_t OFF_W2 = OFF_W1 + SZ_W;
    const size_t OFF_W3 = OFF_W2 + SZ_W;
    const size_t NEED_BIG = OFF_W3 + SZ_W;

    if (ws_size < NEED_BIG) {
        k_fallback<<<NPAIR, 256, 0, stream>>>(x, ei, ew, w1, w2, w3, out);
        return;
    }

    int* meta = (int*)d_ws;
    int* rows = meta + 64;
    unsigned short* H   = (unsigned short*)((char*)d_ws + OFF_H);
    unsigned short* xb  = (unsigned short*)((char*)d_ws + OFF_XB);
    unsigned short* w1t = (unsigned short*)((char*)d_ws + OFF_W1);
    unsigned short* w2t = (unsigned short*)((char*)d_ws + OFF_W2);
    unsigned short* w3t = (unsigned short*)((char*)d_ws + OFF_W3);

    k_sort<<<1, 1024, 0, stream>>>(ei, meta, rows);
    k_prepass<<<14336, 256, 0, stream>>>(x, xb, w1, w1t, w2, w2t, w3, w3t);

    // worst case MT = 72 -> q=9, Sx=9: gemm1 grid = 8*9*16 = 1152; gemm2 = 8*9*8 = 576
    k_gemm1_bf<<<1152, 256, 0, stream>>>(xb, w1t, w2t, meta, rows, H);
    k_gemm2_bf<<<640, 256, 0, stream>>>(H, w3t, meta, rows, ew, out);
}

// Round 5
// 407.296 us; speedup vs baseline: 1.3146x; 1.0287x over previous
//
#include <hip/hip_runtime.h>
#include <hip/hip_bf16.h>

#define N_TOK   4096
#define DM      1024
#define DF      2048
#define NEXP    8
#define NPAIR   (N_TOK * 2)
#define BM      128
#define BN      128
#define BK      32

typedef __attribute__((ext_vector_type(8))) short bf16x8;
typedef __attribute__((ext_vector_type(4))) float f32x4;

__device__ __forceinline__ unsigned short to_bf16(float f) {
    unsigned u = __builtin_bit_cast(unsigned, f);
    unsigned r = (u + 0x7FFFu + ((u >> 16) & 1u)) >> 16;
    return (unsigned short)r;
}
__device__ __forceinline__ unsigned pk_bf16(float a, float b) {
    return (unsigned)to_bf16(a) | ((unsigned)to_bf16(b) << 16);
}
// async global->LDS, 16B per lane; LDS dest = wave-uniform base + lane*16
__device__ __forceinline__ void gld16(const unsigned short* g, unsigned short* l) {
    __builtin_amdgcn_global_load_lds(
        (const __attribute__((address_space(1))) unsigned int*)(g),
        (__attribute__((address_space(3))) unsigned int*)(l), 16, 0, 0);
}

// ---------------- single-kernel sort of pairs by expert ----------------
// meta: [16..25) rowOff, [25..34) mtOff, [34] totalMT
// rows[p] = pair at sorted pos p; pos[pair] = sorted pos (inverse)
__global__ __launch_bounds__(1024)
void k_sort(const int* __restrict__ eidx, int* __restrict__ meta,
            int* __restrict__ rows, int* __restrict__ pos) {
    __shared__ int cnt[NEXP];
    __shared__ int cur[NEXP];
    const int tid = threadIdx.x;
    if (tid < NEXP) cnt[tid] = 0;
    __syncthreads();
    #pragma unroll
    for (int i = tid; i < NPAIR; i += 1024) atomicAdd(&cnt[eidx[i] & 7], 1);
    __syncthreads();
    if (tid == 0) {
        int off = 0, mt = 0;
        for (int e = 0; e < NEXP; ++e) {
            meta[16 + e] = off; meta[25 + e] = mt; cur[e] = off;
            int c = cnt[e];
            off += c; mt += (c + BM - 1) / BM;
        }
        meta[16 + NEXP] = off; meta[25 + NEXP] = mt; meta[34] = mt;
    }
    __syncthreads();
    #pragma unroll
    for (int i = tid; i < NPAIR; i += 1024) {
        int e = eidx[i] & 7;
        int p = atomicAdd(&cur[e], 1);
        rows[p] = i;
        pos[i]  = p;
    }
}

// ---------------- merged pre-pass: x->bf16 + 3 weight transposes ----------------
__device__ __forceinline__ void d_transpose(const float* __restrict__ src,
                                            unsigned short* __restrict__ dst,
                                            int K, int F, int e, int bx, int by,
                                            unsigned short* tile, int t) {
    const int k0 = by * 64;
    const int f0 = bx * 64;
    const float* s = src + (size_t)e * K * F;
    unsigned short* d = dst + (size_t)e * K * F;
    const int fi = t & 63;
    const int kg = t >> 6;
    #pragma unroll
    for (int i = 0; i < 16; ++i) {
        int k = kg * 16 + i;
        tile[k * 80 + fi] = to_bf16(s[(size_t)(k0 + k) * F + f0 + fi]);
    }
    __syncthreads();
    const int kc = (t & 7) * 8;
    const int fo = t >> 3;
    #pragma unroll
    for (int j = 0; j < 2; ++j) {
        int f = fo + j * 32;
        unsigned short v[8];
        #pragma unroll
        for (int i = 0; i < 8; ++i) v[i] = tile[(kc + i) * 80 + f];
        uint4 w;
        w.x = (unsigned)v[0] | ((unsigned)v[1] << 16);
        w.y = (unsigned)v[2] | ((unsigned)v[3] << 16);
        w.z = (unsigned)v[4] | ((unsigned)v[5] << 16);
        w.w = (unsigned)v[6] | ((unsigned)v[7] << 16);
        *(uint4*)&d[(size_t)(f0 + f) * K + k0 + kc] = w;
    }
}

// blocks: [0,2048) cvt_x | [2048,6144) w1 | [6144,10240) w2 | [10240,14336) w3
__global__ __launch_bounds__(256)
void k_prepass(const float* __restrict__ x, unsigned short* __restrict__ xb,
               const float* __restrict__ w1, unsigned short* __restrict__ w1t,
               const float* __restrict__ w2, unsigned short* __restrict__ w2t,
               const float* __restrict__ w3, unsigned short* __restrict__ w3t) {
    __shared__ __align__(16) unsigned short tile[64 * 80];
    const int b = blockIdx.x;
    const int t = threadIdx.x;
    if (b < 2048) {
        int i = (b * 256 + t) * 8;
        float4 v0 = *(const float4*)(x + i);
        float4 v1 = *(const float4*)(x + i + 4);
        uint4 w;
        w.x = pk_bf16(v0.x, v0.y); w.y = pk_bf16(v0.z, v0.w);
        w.z = pk_bf16(v1.x, v1.y); w.w = pk_bf16(v1.z, v1.w);
        *(uint4*)(xb + i) = w;
    } else if (b < 6144) {
        int l = b - 2048;            // K=DM (16 y-blocks), F=DF (32 x-blocks), 512/e
        int e = l >> 9, rem = l & 511;
        d_transpose(w1, w1t, DM, DF, e, rem & 31, rem >> 5, tile, t);
    } else if (b < 10240) {
        int l = b - 6144;
        int e = l >> 9, rem = l & 511;
        d_transpose(w2, w2t, DM, DF, e, rem & 31, rem >> 5, tile, t);
    } else {
        int l = b - 10240;           // K=DF (32 y-blocks), F=DM (16 x-blocks), 512/e
        int e = l >> 9, rem = l & 511;
        d_transpose(w3, w3t, DF, DM, e, rem & 15, rem >> 4, tile, t);
    }
}

// ---------------- bf16 GEMM1: H = silu(X W1) * (X W2) ----------------
__global__ __launch_bounds__(256, 2)
void k_gemm1_bf(const unsigned short* __restrict__ xb,
                const unsigned short* __restrict__ w1t,  // [E][F][K=DM]
                const unsigned short* __restrict__ w2t,
                const int* __restrict__ meta,
                const int* __restrict__ rows,
                unsigned short* __restrict__ H)
{
    __shared__ __align__(16) unsigned short As [BM * BK];
    __shared__ __align__(16) unsigned short B1s[BN * BK];
    __shared__ __align__(16) unsigned short B2s[BN * BK];
    __shared__ int s_tok[BM];

    const int mt = blockIdx.y;
    if (mt >= meta[34]) return;
    int e = 0;
    #pragma unroll
    for (int i = 0; i < NEXP - 1; ++i) if (mt >= meta[25 + i + 1]) e = i + 1;
    const int rowEnd = meta[16 + e + 1];
    const int row0   = meta[16 + e] + (mt - meta[25 + e]) * BM;
    const int f0     = blockIdx.x * BN;
    const int tid    = threadIdx.x;

    if (tid < BM) {
        int gr = row0 + tid;
        s_tok[tid] = (gr < rowEnd) ? (rows[gr] >> 1) : 0;
    }
    __syncthreads();

    const int lane = tid & 63;
    const int wave = tid >> 6;
    const int r0 = wave * 32 + (lane >> 2);
    const int r1 = r0 + 16;
    const int kb = (lane & 3) * 8;
    const unsigned short* a_src0 = xb + (size_t)s_tok[r0] * DM + kb;
    const unsigned short* a_src1 = xb + (size_t)s_tok[r1] * DM + kb;
    const size_t wb = (size_t)e * DM * DF;
    const unsigned short* b1_src0 = w1t + wb + (size_t)(f0 + r0) * DM + kb;
    const unsigned short* b1_src1 = w1t + wb + (size_t)(f0 + r1) * DM + kb;
    const unsigned short* b2_src0 = w2t + wb + (size_t)(f0 + r0) * DM + kb;
    const unsigned short* b2_src1 = w2t + wb + (size_t)(f0 + r1) * DM + kb;
    unsigned short* As0  = &As [wave * 1024];
    unsigned short* As1  = &As [wave * 1024 + 512];
    unsigned short* B1s0 = &B1s[wave * 1024];
    unsigned short* B1s1 = &B1s[wave * 1024 + 512];
    unsigned short* B2s0 = &B2s[wave * 1024];
    unsigned short* B2s1 = &B2s[wave * 1024 + 512];

    f32x4 accg[4][4], accv[4][4];
    #pragma unroll
    for (int i = 0; i < 4; ++i)
        #pragma unroll
        for (int j = 0; j < 4; ++j) { accg[i][j] = (f32x4)0.f; accv[i][j] = (f32x4)0.f; }

    const int wm = (wave >> 1) * 64;
    const int wn = (wave & 1) * 64;
    const int am = lane & 15;
    const int ak = (lane >> 4) * 8;

    for (int k0 = 0; k0 < DM; k0 += BK) {
        gld16(a_src0 + k0, As0);
        gld16(a_src1 + k0, As1);
        gld16(b1_src0 + k0, B1s0);
        gld16(b1_src1 + k0, B1s1);
        gld16(b2_src0 + k0, B2s0);
        gld16(b2_src1 + k0, B2s1);
        __syncthreads();

        bf16x8 a[4], b1[4], b2[4];
        #pragma unroll
        for (int mi = 0; mi < 4; ++mi) a[mi] = *(const bf16x8*)&As[(wm + mi * 16 + am) * BK + ak];
        #pragma unroll
        for (int ni = 0; ni < 4; ++ni) {
            b1[ni] = *(const bf16x8*)&B1s[(wn + ni * 16 + am) * BK + ak];
            b2[ni] = *(const bf16x8*)&B2s[(wn + ni * 16 + am) * BK + ak];
        }
        #pragma unroll
        for (int mi = 0; mi < 4; ++mi)
            #pragma unroll
            for (int ni = 0; ni < 4; ++ni) {
                accg[mi][ni] = __builtin_amdgcn_mfma_f32_16x16x32_bf16(a[mi], b1[ni], accg[mi][ni], 0, 0, 0);
                accv[mi][ni] = __builtin_amdgcn_mfma_f32_16x16x32_bf16(a[mi], b2[ni], accv[mi][ni], 0, 0, 0);
            }
        __syncthreads();
    }

    const int cn = lane & 15;
    const int cq = (lane >> 4) * 4;
    #pragma unroll
    for (int mi = 0; mi < 4; ++mi) {
        #pragma unroll
        for (int r = 0; r < 4; ++r) {
            const int row = wm + mi * 16 + cq + r;
            const int gr  = row0 + row;
            if (gr < rowEnd) {
                unsigned short* dst = H + (size_t)gr * DF + f0 + wn;
                #pragma unroll
                for (int ni = 0; ni < 4; ++ni) {
                    float g = accg[mi][ni][r];
                    float v = accv[mi][ni][r];
                    float h = (g * v) / (1.f + __expf(-g));
                    dst[ni * 16 + cn] = to_bf16(h);
                }
            }
        }
    }
}

// ---------------- bf16 GEMM2: S[gr] = w * (H @ W3)   (plain stores, no atomics) ----------------
__global__ __launch_bounds__(256, 2)
void k_gemm2_bf(const unsigned short* __restrict__ H,
                const unsigned short* __restrict__ w3t,  // [E][D=DM][K=DF]
                const int* __restrict__ meta,
                const int* __restrict__ rows,
                const float* __restrict__ ew,
                float* __restrict__ S)                   // [NPAIR][DM] fp32
{
    __shared__ __align__(16) unsigned short As[BM * BK];
    __shared__ __align__(16) unsigned short Bs[BN * BK];
    __shared__ int   s_tok[BM];
    __shared__ float s_w[BM];

    const int mt = blockIdx.y;
    if (mt >= meta[34]) return;
    int e = 0;
    #pragma unroll
    for (int i = 0; i < NEXP - 1; ++i) if (mt >= meta[25 + i + 1]) e = i + 1;
    const int rowEnd = meta[16 + e + 1];
    const int row0   = meta[16 + e] + (mt - meta[25 + e]) * BM;
    const int d0     = blockIdx.x * BN;
    const int tid    = threadIdx.x;

    if (tid < BM) {
        int gr = row0 + tid;
        if (gr < rowEnd) { int pr = rows[gr]; s_tok[tid] = pr >> 1; s_w[tid] = ew[pr]; }
        else             { s_tok[tid] = 0;    s_w[tid] = 0.f; }
    }
    __syncthreads();

    const int lane = tid & 63;
    const int wave = tid >> 6;
    const int r0 = wave * 32 + (lane >> 2);
    const int r1 = r0 + 16;
    const int kb = (lane & 3) * 8;
    int gr0 = row0 + r0; if (gr0 > NPAIR - 1) gr0 = NPAIR - 1;
    int gr1 = row0 + r1; if (gr1 > NPAIR - 1) gr1 = NPAIR - 1;
    const unsigned short* a_src0 = H + (size_t)gr0 * DF + kb;
    const unsigned short* a_src1 = H + (size_t)gr1 * DF + kb;
    const size_t wb = (size_t)e * DM * DF;
    const unsigned short* b_src0 = w3t + wb + (size_t)(d0 + r0) * DF + kb;
    const unsigned short* b_src1 = w3t + wb + (size_t)(d0 + r1) * DF + kb;
    unsigned short* As0 = &As[wave * 1024];
    unsigned short* As1 = &As[wave * 1024 + 512];
    unsigned short* Bs0 = &Bs[wave * 1024];
    unsigned short* Bs1 = &Bs[wave * 1024 + 512];

    f32x4 acc[4][4];
    #pragma unroll
    for (int i = 0; i < 4; ++i)
        #pragma unroll
        for (int j = 0; j < 4; ++j) acc[i][j] = (f32x4)0.f;

    const int wm = (wave >> 1) * 64;
    const int wn = (wave & 1) * 64;
    const int am = lane & 15;
    const int ak = (lane >> 4) * 8;

    for (int k0 = 0; k0 < DF; k0 += BK) {
        gld16(a_src0 + k0, As0);
        gld16(a_src1 + k0, As1);
        gld16(b_src0 + k0, Bs0);
        gld16(b_src1 + k0, Bs1);
        __syncthreads();

        bf16x8 a[4], b[4];
        #pragma unroll
        for (int mi = 0; mi < 4; ++mi) a[mi] = *(const bf16x8*)&As[(wm + mi * 16 + am) * BK + ak];
        #pragma unroll
        for (int ni = 0; ni < 4; ++ni) b[ni] = *(const bf16x8*)&Bs[(wn + ni * 16 + am) * BK + ak];
        #pragma unroll
        for (int mi = 0; mi < 4; ++mi)
            #pragma unroll
            for (int ni = 0; ni < 4; ++ni)
                acc[mi][ni] = __builtin_amdgcn_mfma_f32_16x16x32_bf16(a[mi], b[ni], acc[mi][ni], 0, 0, 0);
        __syncthreads();
    }

    const int cn = lane & 15;
    const int cq = (lane >> 4) * 4;
    #pragma unroll
    for (int mi = 0; mi < 4; ++mi) {
        #pragma unroll
        for (int r = 0; r < 4; ++r) {
            const int row = wm + mi * 16 + cq + r;
            const int gr  = row0 + row;
            if (gr < rowEnd) {
                const float wgt = s_w[row];
                float* dst = S + (size_t)gr * DM + d0 + wn;
                #pragma unroll
                for (int ni = 0; ni < 4; ++ni)
                    dst[ni * 16 + cn] = wgt * acc[mi][ni][r];
            }
        }
    }
}

// ---------------- combine: out[t] = S[pos[2t]] + S[pos[2t+1]] ----------------
__global__ __launch_bounds__(256)
void k_combine(const float* __restrict__ S, const int* __restrict__ pos,
               float* __restrict__ out) {
    const int idx = blockIdx.x * 256 + threadIdx.x;   // one float4 per thread
    const int t   = idx >> 8;                         // DM/4 = 256 float4 per token
    const int d4  = idx & 255;
    const int p0 = pos[2 * t];
    const int p1 = pos[2 * t + 1];
    const float4 a = *(const float4*)(S + (size_t)p0 * DM + d4 * 4);
    const float4 b = *(const float4*)(S + (size_t)p1 * DM + d4 * 4);
    float4 o;
    o.x = a.x + b.x; o.y = a.y + b.y; o.z = a.z + b.z; o.w = a.w + b.w;
    *(float4*)(out + (size_t)t * DM + d4 * 4) = o;
}

// ================= fallback (tiny workspace) =================
__global__ __launch_bounds__(256)
void k_fallback(const float* __restrict__ x, const int* __restrict__ eidx,
                const float* __restrict__ ew, const float* __restrict__ w1,
                const float* __restrict__ w2, const float* __restrict__ w3,
                float* __restrict__ out)
{
    __shared__ float xs[DM];
    __shared__ float hs[DF];
    const int pair = blockIdx.x;
    const int t = pair >> 1;
    const int e = eidx[pair] & 7;
    const float wgt = ew[pair];
    const int tid = threadIdx.x;
    for (int i = tid; i < DM; i += 256) xs[i] = x[(size_t)t * DM + i];
    __syncthreads();
    for (int f = tid; f < DF; f += 256) {
        const float* c1 = w1 + (size_t)e * DM * DF + f;
        const float* c2 = w2 + (size_t)e * DM * DF + f;
        float g = 0.f, v = 0.f;
        for (int d = 0; d < DM; ++d) {
            float xv = xs[d];
            g += xv * c1[(size_t)d * DF];
            v += xv * c2[(size_t)d * DF];
        }
        hs[f] = (g * v) / (1.f + __expf(-g));
    }
    __syncthreads();
    for (int d = tid; d < DM; d += 256) {
        const float* c3 = w3 + (size_t)e * DF * DM + d;
        float o = 0.f;
        for (int f = 0; f < DF; ++f) o += hs[f] * c3[(size_t)f * DM];
        atomicAdd(&out[(size_t)t * DM + d], wgt * o);
    }
}

extern "C" void kernel_launch(void* const* d_in, const int* in_sizes, int n_in,
                              void* d_out, int out_size, void* d_ws, size_t ws_size,
                              hipStream_t stream)
{
    const float* x  = (const float*)d_in[0];
    const int*   ei = (const int*)  d_in[1];
    const float* ew = (const float*)d_in[2];
    const float* w1 = (const float*)d_in[3];
    const float* w2 = (const float*)d_in[4];
    const float* w3 = (const float*)d_in[5];
    float* out = (float*)d_out;

    const size_t SZ_H  = (size_t)NPAIR * DF * 2;     // 32 MB
    const size_t SZ_XB = (size_t)N_TOK * DM * 2;     // 8 MB
    const size_t SZ_W  = (size_t)NEXP * DM * DF * 2; // 32 MB each
    const size_t OFF_H  = 131072;                    // meta+rows+pos live below
    const size_t OFF_XB = OFF_H + SZ_H;
    const size_t OFF_W1 = OFF_XB + SZ_XB;
    const size_t OFF_W2 = OFF_W1 + SZ_W;
    const size_t OFF_W3 = OFF_W2 + SZ_W;
    const size_t NEED_BIG = OFF_W3 + SZ_W;

    if (ws_size < NEED_BIG) {
        (void)hipMemsetAsync(d_out, 0, (size_t)out_size * sizeof(float), stream);
        k_fallback<<<NPAIR, 256, 0, stream>>>(x, ei, ew, w1, w2, w3, out);
        return;
    }

    int* meta = (int*)d_ws;
    int* rows = meta + 64;
    int* pos  = rows + NPAIR;
    unsigned short* H   = (unsigned short*)((char*)d_ws + OFF_H);
    unsigned short* xb  = (unsigned short*)((char*)d_ws + OFF_XB);
    unsigned short* w1t = (unsigned short*)((char*)d_ws + OFF_W1);
    unsigned short* w2t = (unsigned short*)((char*)d_ws + OFF_W2);
    unsigned short* w3t = (unsigned short*)((char*)d_ws + OFF_W3);
    // S aliases w1t: w1t is dead once gemm1 completes; S (32 MB fp32) fits exactly.
    float* S = (float*)((char*)d_ws + OFF_W1);

    k_sort<<<1, 1024, 0, stream>>>(ei, meta, rows, pos);
    k_prepass<<<14336, 256, 0, stream>>>(x, xb, w1, w1t, w2, w2t, w3, w3t);

    const int NMT = NPAIR / BM + NEXP;  // 72 worst-case m-tiles
    k_gemm1_bf<<<dim3(DF / BN, NMT), 256, 0, stream>>>(xb, w1t, w2t, meta, rows, H);
    k_gemm2_bf<<<dim3(DM / BN, NMT), 256, 0, stream>>>(H, w3t, meta, rows, ew, S);
    k_combine<<<(N_TOK * DM / 4) / 256, 256, 0, stream>>>(S, pos, out);
}